// Round 7
// baseline (2566.957 us; speedup 1.0000x reference)
//
#include <hip/hip_runtime.h>
#include <hip/hip_bf16.h>
#include <stdint.h>

#define M_DIM 8192
#define N_DIM 4096   // OUT_F
#define K_DIM 4096   // IN_F

#define BM 256
#define BN 256
#define BK 32
#define NT (K_DIM / BK)   // 128 K-tiles

typedef __bf16 bf16_t;
typedef __attribute__((ext_vector_type(8))) __bf16 bf16x8;
typedef __attribute__((ext_vector_type(4))) float f32x4;

// ---------------- fp32 -> bf16 convert (vectorized, grid-stride) ----------------
__global__ void cvt_f32_to_bf16(const float* __restrict__ in, bf16_t* __restrict__ out, int n8) {
    int stride = gridDim.x * blockDim.x;
    for (int i = blockIdx.x * blockDim.x + threadIdx.x; i < n8; i += stride) {
        const float4* p = reinterpret_cast<const float4*>(in) + 2 * (size_t)i;
        float4 v0 = p[0];
        float4 v1 = p[1];
        bf16x8 o;
        o[0] = (bf16_t)v0.x; o[1] = (bf16_t)v0.y; o[2] = (bf16_t)v0.z; o[3] = (bf16_t)v0.w;
        o[4] = (bf16_t)v1.x; o[5] = (bf16_t)v1.y; o[6] = (bf16_t)v1.z; o[7] = (bf16_t)v1.w;
        *(reinterpret_cast<bf16x8*>(out) + (size_t)i) = o;
    }
}

// ---------------- 256x256 bf16 GEMM, 2-deep ring, 2 blocks/CU ----------------
// A: [M][K] bf16 row-major; B: [N][K] bf16 row-major (weight = B^T layout);
// C = A*B^T + bias, fp32 out.
//
// KEY CHANGE vs r2-r6: LDS shrunk to a 2-deep ring (64 KiB) so TWO blocks
// co-reside per CU (grid 512 = 2 x 256 CUs, 4 waves/SIMD). Cross-block
// desync makes one block's ds_read/stage burst overlap the other block's
// MFMA burst (m114 mechanism) -- no intra-block scheduling needed.
// Per tile, ONE barrier + ONE vmcnt(0):
//   [STAGE(T+1) issued at top (4 global_load_lds, issue-early)]
//   [12 ds_read_b128] [32 MFMA, setprio-wrapped, compiler-scheduled lgkmcnt]
//   vmcnt(0)  -> tile T+1's staged data landed
//   s_barrier -> publishes T+1; also closes WAR: this tile's reads of
//                buf[T&1] all completed before each wave reached here
//                (ds_read -> MFMA issue is lgkmcnt-ordered), so next tile's
//                STAGE(T+2) may overwrite buf[T&1].

#define MF(a, b, c) __builtin_amdgcn_mfma_f32_16x16x32_bf16((a), (b), (c), 0, 0, 0)
#define LD8(p) (*reinterpret_cast<const bf16x8*>(p))

#define STAGE_A(T) {                                                                  \
    const int sb_ = (T) & 1; const size_t kof_ = (size_t)(T) * BK;                    \
    __builtin_amdgcn_global_load_lds(                                                 \
        (const __attribute__((address_space(1))) void*)(gA0 + kof_),                  \
        (__attribute__((address_space(3))) void*)(&Asm[sb_][dst0]), 16, 0, 0);        \
    __builtin_amdgcn_global_load_lds(                                                 \
        (const __attribute__((address_space(1))) void*)(gA1 + kof_),                  \
        (__attribute__((address_space(3))) void*)(&Asm[sb_][dst1]), 16, 0, 0);        \
}

#define STAGE_B(T) {                                                                  \
    const int sb_ = (T) & 1; const size_t kof_ = (size_t)(T) * BK;                    \
    __builtin_amdgcn_global_load_lds(                                                 \
        (const __attribute__((address_space(1))) void*)(gB0 + kof_),                  \
        (__attribute__((address_space(3))) void*)(&Bsm[sb_][dst0]), 16, 0, 0);        \
    __builtin_amdgcn_global_load_lds(                                                 \
        (const __attribute__((address_space(1))) void*)(gB1 + kof_),                  \
        (__attribute__((address_space(3))) void*)(&Bsm[sb_][dst1]), 16, 0, 0);        \
}

#define TILE(T, STG, VMSTR) do {                                                      \
    bf16_t* Al_ = &Asm[(T) & 1][0];                                                   \
    bf16_t* Bl_ = &Bsm[(T) & 1][0];                                                   \
    if (STG) { STAGE_A((T) + 1); STAGE_B((T) + 1); }                                  \
    bf16x8 a0_ = LD8(Al_ + oa0), a1_ = LD8(Al_ + oa1);                                \
    bf16x8 a2_ = LD8(Al_ + oa2), a3_ = LD8(Al_ + oa3);                                \
    bf16x8 b0_ = LD8(Bl_ + ob0), b1_ = LD8(Bl_ + ob1);                                \
    bf16x8 b2_ = LD8(Bl_ + ob2), b3_ = LD8(Bl_ + ob3);                                \
    bf16x8 a4_ = LD8(Al_ + oa4), a5_ = LD8(Al_ + oa5);                                \
    bf16x8 a6_ = LD8(Al_ + oa6), a7_ = LD8(Al_ + oa7);                                \
    __builtin_amdgcn_s_setprio(1);                                                    \
    acc[0][0]=MF(a0_,b0_,acc[0][0]); acc[0][1]=MF(a0_,b1_,acc[0][1]);                 \
    acc[0][2]=MF(a0_,b2_,acc[0][2]); acc[0][3]=MF(a0_,b3_,acc[0][3]);                 \
    acc[1][0]=MF(a1_,b0_,acc[1][0]); acc[1][1]=MF(a1_,b1_,acc[1][1]);                 \
    acc[1][2]=MF(a1_,b2_,acc[1][2]); acc[1][3]=MF(a1_,b3_,acc[1][3]);                 \
    acc[2][0]=MF(a2_,b0_,acc[2][0]); acc[2][1]=MF(a2_,b1_,acc[2][1]);                 \
    acc[2][2]=MF(a2_,b2_,acc[2][2]); acc[2][3]=MF(a2_,b3_,acc[2][3]);                 \
    acc[3][0]=MF(a3_,b0_,acc[3][0]); acc[3][1]=MF(a3_,b1_,acc[3][1]);                 \
    acc[3][2]=MF(a3_,b2_,acc[3][2]); acc[3][3]=MF(a3_,b3_,acc[3][3]);                 \
    acc[4][0]=MF(a4_,b0_,acc[4][0]); acc[4][1]=MF(a4_,b1_,acc[4][1]);                 \
    acc[4][2]=MF(a4_,b2_,acc[4][2]); acc[4][3]=MF(a4_,b3_,acc[4][3]);                 \
    acc[5][0]=MF(a5_,b0_,acc[5][0]); acc[5][1]=MF(a5_,b1_,acc[5][1]);                 \
    acc[5][2]=MF(a5_,b2_,acc[5][2]); acc[5][3]=MF(a5_,b3_,acc[5][3]);                 \
    acc[6][0]=MF(a6_,b0_,acc[6][0]); acc[6][1]=MF(a6_,b1_,acc[6][1]);                 \
    acc[6][2]=MF(a6_,b2_,acc[6][2]); acc[6][3]=MF(a6_,b3_,acc[6][3]);                 \
    acc[7][0]=MF(a7_,b0_,acc[7][0]); acc[7][1]=MF(a7_,b1_,acc[7][1]);                 \
    acc[7][2]=MF(a7_,b2_,acc[7][2]); acc[7][3]=MF(a7_,b3_,acc[7][3]);                 \
    __builtin_amdgcn_s_setprio(0);                                                    \
    asm volatile(VMSTR ::: "memory");                                                 \
    __builtin_amdgcn_s_barrier();                                                     \
} while (0)

__global__ __launch_bounds__(512, 4) void gemm_bf16_2cu(
        const bf16_t* __restrict__ A, const bf16_t* __restrict__ B,
        const float* __restrict__ bias, float* __restrict__ C) {

    __shared__ __align__(16) bf16_t Asm[2][BM * BK];   // 2 x 16 KB
    __shared__ __align__(16) bf16_t Bsm[2][BN * BK];   // 2 x 16 KB  -> 64 KiB total

    const int tid  = threadIdx.x;
    const int lane = tid & 63;
    const int wave = tid >> 6;        // 0..7
    const int wm   = wave >> 2;       // 0..1 : M half (128 rows)
    const int wn   = wave & 3;        // 0..3 : N quarter (64 cols)

    // XCD-aware swizzle (nwg = 512, divisible by 8 -> bijective)
    const int nwg = gridDim.x;
    const int cpx = nwg >> 3;
    const int swz = (blockIdx.x & 7) * cpx + (blockIdx.x >> 3);
    const int ntn = N_DIM / BN;       // 16
    const int brow = (swz / ntn) * BM;
    const int bcol = (swz % ntn) * BN;

    // ---- staging geometry (r2-proven): tile = 256 rows x 32 bf16 = 16KB =
    // 1024 x 16B slots; slot s holds (row = s>>2, chunk = (s&3)^((s>>3)&3)).
    const int slot0 = wave * 128 + lane;
    const int slot1 = slot0 + 64;
    const int r0 = slot0 >> 2, c0 = ((slot0 & 3) ^ ((slot0 >> 3) & 3)) << 3;
    const int r1 = slot1 >> 2, c1 = ((slot1 & 3) ^ ((slot1 >> 3) & 3)) << 3;
    const bf16_t* gA0 = A + (size_t)(brow + r0) * K_DIM + c0;
    const bf16_t* gA1 = A + (size_t)(brow + r1) * K_DIM + c1;
    const bf16_t* gB0 = B + (size_t)(bcol + r0) * K_DIM + c0;
    const bf16_t* gB1 = B + (size_t)(bcol + r1) * K_DIM + c1;
    const int dst0 = wave * 1024;     // elem offset (slot * 8)
    const int dst1 = dst0 + 512;

    // ---- ds_read fragment offsets (r2-proven, measured 0 bank conflicts)
    const int fr = lane & 15;
    const int cc = lane >> 4;         // k-chunk 0..3 (k = cc*8)
#define AOFF(p, mi) ({ int row_ = wm*128 + (p)*64 + (mi)*16 + fr; \
                       row_*32 + ((cc ^ ((row_ >> 1) & 3)) << 3); })
#define BOFF(ni)    ({ int row_ = wn*64 + (ni)*16 + fr; \
                       row_*32 + ((cc ^ ((row_ >> 1) & 3)) << 3); })
    const int oa0 = AOFF(0,0), oa1 = AOFF(0,1), oa2 = AOFF(0,2), oa3 = AOFF(0,3);
    const int oa4 = AOFF(1,0), oa5 = AOFF(1,1), oa6 = AOFF(1,2), oa7 = AOFF(1,3);
    const int ob0 = BOFF(0), ob1 = BOFF(1), ob2 = BOFF(2), ob3 = BOFF(3);

    f32x4 acc[8][4];
#pragma unroll
    for (int i = 0; i < 8; i++)
#pragma unroll
        for (int j = 0; j < 4; j++)
            acc[i][j] = (f32x4){0.f, 0.f, 0.f, 0.f};

    // ---- prologue: stage tile 0, land it
    STAGE_A(0) STAGE_B(0)
    asm volatile("s_waitcnt vmcnt(0)" ::: "memory");
    __builtin_amdgcn_s_barrier();

    // ---- main loop: one barrier + one vmcnt(0) per tile
    for (int t = 0; t < NT - 1; ++t)
        TILE(t, 1, "s_waitcnt vmcnt(0)");
    TILE(NT - 1, 0, "s_nop 0");

    // ---- epilogue: C/D layout col = lane&15, row = (lane>>4)*4 + r
    const int cc0 = bcol + wn * 64 + (lane & 15);
    const int rr0 = brow + wm * 128 + (lane >> 4) * 4;

    float bv[4];
#pragma unroll
    for (int ni = 0; ni < 4; ni++) bv[ni] = bias[cc0 + ni * 16];

#pragma unroll
    for (int p = 0; p < 2; p++) {
#pragma unroll
        for (int i = 0; i < 4; i++) {
#pragma unroll
            for (int r = 0; r < 4; r++) {
                const size_t row = (size_t)(rr0 + p * 64 + i * 16 + r);
#pragma unroll
                for (int ni = 0; ni < 4; ni++) {
                    C[row * N_DIM + cc0 + ni * 16] = acc[p * 4 + i][ni][r] + bv[ni];
                }
            }
        }
    }
}

// ---------------- safety-net fallback (no workspace): plain fp32 dot ----------------
__global__ void gemm_fallback_f32(const float* __restrict__ A, const float* __restrict__ B,
                                  const float* __restrict__ bias, float* __restrict__ C) {
    int n = blockIdx.x * 16 + threadIdx.x;
    int m = blockIdx.y * 16 + threadIdx.y;
    if (m >= M_DIM || n >= N_DIM) return;
    const float4* a = reinterpret_cast<const float4*>(A + (size_t)m * K_DIM);
    const float4* b = reinterpret_cast<const float4*>(B + (size_t)n * K_DIM);
    float s = 0.f;
    for (int k = 0; k < K_DIM / 4; k++) {
        float4 x = a[k], y = b[k];
        s += x.x * y.x + x.y * y.y + x.z * y.z + x.w * y.w;
    }
    C[(size_t)m * N_DIM + n] = s + bias[n];
}

extern "C" void kernel_launch(void* const* d_in, const int* in_sizes, int n_in,
                              void* d_out, int out_size, void* d_ws, size_t ws_size,
                              hipStream_t stream) {
    const float* x    = (const float*)d_in[0];   // [M][K] fp32
    const float* w    = (const float*)d_in[1];   // [N][K] fp32 (B^T layout)
    const float* bias = (const float*)d_in[2];   // [N] fp32
    float* out = (float*)d_out;

    const size_t xb = (size_t)M_DIM * K_DIM * sizeof(bf16_t);   // 64 MB
    const size_t wb = (size_t)N_DIM * K_DIM * sizeof(bf16_t);   // 32 MB

    if (ws_size >= xb + wb) {
        bf16_t* xbf = (bf16_t*)d_ws;
        bf16_t* wbf = (bf16_t*)((char*)d_ws + xb);

        cvt_f32_to_bf16<<<2048, 256, 0, stream>>>(x, xbf, (M_DIM * K_DIM) / 8);
        cvt_f32_to_bf16<<<1024, 256, 0, stream>>>(w, wbf, (N_DIM * K_DIM) / 8);

        const int grid = (M_DIM / BM) * (N_DIM / BN);   // 32 * 16 = 512 = 2/CU
        gemm_bf16_2cu<<<grid, 512, 0, stream>>>(xbf, wbf, bias, out);
    } else {
        dim3 block(16, 16);
        dim3 grid(N_DIM / 16, M_DIM / 16);
        gemm_fallback_f32<<<grid, block, 0, stream>>>(x, w, bias, out);
    }
}

// Round 8
// 337.272 us; speedup vs baseline: 7.6109x; 7.6109x over previous
//
#include <hip/hip_runtime.h>
#include <hip/hip_bf16.h>
#include <stdint.h>

#define M_DIM 8192
#define N_DIM 4096   // OUT_F
#define K_DIM 4096   // IN_F

#define BM 256
#define BN 256
#define BK 32
#define NT (K_DIM / BK)   // 128 K-tiles
#define NBUF 4

typedef __bf16 bf16_t;
typedef __attribute__((ext_vector_type(8))) __bf16 bf16x8;
typedef __attribute__((ext_vector_type(4))) float f32x4;

// ---------------- fp32 -> bf16 convert (vectorized, grid-stride) ----------------
__global__ void cvt_f32_to_bf16(const float* __restrict__ in, bf16_t* __restrict__ out, int n8) {
    int stride = gridDim.x * blockDim.x;
    for (int i = blockIdx.x * blockDim.x + threadIdx.x; i < n8; i += stride) {
        const float4* p = reinterpret_cast<const float4*>(in) + 2 * (size_t)i;
        float4 v0 = p[0];
        float4 v1 = p[1];
        bf16x8 o;
        o[0] = (bf16_t)v0.x; o[1] = (bf16_t)v0.y; o[2] = (bf16_t)v0.z; o[3] = (bf16_t)v0.w;
        o[4] = (bf16_t)v1.x; o[5] = (bf16_t)v1.y; o[6] = (bf16_t)v1.z; o[7] = (bf16_t)v1.w;
        *(reinterpret_cast<bf16x8*>(out) + (size_t)i) = o;
    }
}

// ---------------- 256x256 bf16 GEMM: dependency-free MFMA pipeline ----------------
// A: [M][K] bf16 row-major; B: [N][K] bf16 row-major (weight = B^T layout);
// C = A*B^T + bias, fp32 out.
//
// 4-deep ring; ONE vmcnt + ONE barrier per tile, both at tile TOP; stage AFTER
// the barrier. Body: all ds_reads feed FUTURE MFMA clusters; both 16-MFMA
// clusters use operands read >=1 cluster earlier -> no lgkmcnt stall ever, so
// the LDS pipe drains under the matrix pipe.
//   WAR: stage at top of T (post-barrier) writes buf[(T+3)&3] = buf[(T-1)&3].
//        In-flight reads at barrier-release can only be body-(T-1)'s reads of
//        buf[T] (read-ahead) -- disjoint. x-reads of buf[T-1] were drained by
//        their consuming cluster-2 MFMAs before each wave reached the barrier.
//   RAW: at top-of-T vmcnt point, outstanding = {T+1 (staged top T-2),
//        T+2 (staged top T-1)} = 8 -> vmcnt(4) drains T+1, which body-T's
//        read-ahead consumes after the barrier publishes it.
//   Tail: top-125 vmcnt(4) (drains 126), top-126 vmcnt(0) (drains 127),
//        top-127 none; stages stop at top-124 (stages tile 127).

#define MF(a, b, c) __builtin_amdgcn_mfma_f32_16x16x32_bf16((a), (b), (c), 0, 0, 0)
#define LD8(p) (*reinterpret_cast<const bf16x8*>(p))

#define STAGE_A(T) {                                                                  \
    const int sb_ = (T) & 3; const size_t kof_ = (size_t)(T) * BK;                    \
    __builtin_amdgcn_global_load_lds(                                                 \
        (const __attribute__((address_space(1))) void*)(gA0 + kof_),                  \
        (__attribute__((address_space(3))) void*)(&Asm[sb_][dst0]), 16, 0, 0);        \
    __builtin_amdgcn_global_load_lds(                                                 \
        (const __attribute__((address_space(1))) void*)(gA1 + kof_),                  \
        (__attribute__((address_space(3))) void*)(&Asm[sb_][dst1]), 16, 0, 0);        \
}

#define STAGE_B(T) {                                                                  \
    const int sb_ = (T) & 3; const size_t kof_ = (size_t)(T) * BK;                    \
    __builtin_amdgcn_global_load_lds(                                                 \
        (const __attribute__((address_space(1))) void*)(gB0 + kof_),                  \
        (__attribute__((address_space(3))) void*)(&Bsm[sb_][dst0]), 16, 0, 0);        \
    __builtin_amdgcn_global_load_lds(                                                 \
        (const __attribute__((address_space(1))) void*)(gB1 + kof_),                  \
        (__attribute__((address_space(3))) void*)(&Bsm[sb_][dst1]), 16, 0, 0);        \
}

// BC0-3: carried B frags for THIS tile; BN0-3: read-ahead B frags for T+1.
// aC0-3 (named vars): carried A frags for this tile's cluster 1, reloaded
// in-place after cluster 1 for tile T+1 (register dependency orders it).
#define TILE(T, STG, VMSTR, RA, BC0,BC1,BC2,BC3, BN0,BN1,BN2,BN3) do {                \
    asm volatile(VMSTR ::: "memory");                                                 \
    __builtin_amdgcn_s_barrier();                                                     \
    if (STG) { STAGE_A((T) + 3); STAGE_B((T) + 3); }                                  \
    bf16_t* Al_ = &Asm[(T) & 3][0];                                                   \
    bf16_t* An_ = &Asm[((T) + 1) & 3][0];                                             \
    bf16_t* Bn_ = &Bsm[((T) + 1) & 3][0];                                             \
    bf16x8 x4_ = LD8(Al_ + oa4), x5_ = LD8(Al_ + oa5);                                \
    bf16x8 x6_ = LD8(Al_ + oa6), x7_ = LD8(Al_ + oa7);                                \
    if (RA) { BN0 = LD8(Bn_ + ob0); BN1 = LD8(Bn_ + ob1);                             \
              BN2 = LD8(Bn_ + ob2); BN3 = LD8(Bn_ + ob3); }                           \
    __builtin_amdgcn_s_setprio(1);                                                    \
    acc[0][0]=MF(aC0,BC0,acc[0][0]); acc[0][1]=MF(aC0,BC1,acc[0][1]);                 \
    acc[0][2]=MF(aC0,BC2,acc[0][2]); acc[0][3]=MF(aC0,BC3,acc[0][3]);                 \
    acc[1][0]=MF(aC1,BC0,acc[1][0]); acc[1][1]=MF(aC1,BC1,acc[1][1]);                 \
    acc[1][2]=MF(aC1,BC2,acc[1][2]); acc[1][3]=MF(aC1,BC3,acc[1][3]);                 \
    acc[2][0]=MF(aC2,BC0,acc[2][0]); acc[2][1]=MF(aC2,BC1,acc[2][1]);                 \
    acc[2][2]=MF(aC2,BC2,acc[2][2]); acc[2][3]=MF(aC2,BC3,acc[2][3]);                 \
    acc[3][0]=MF(aC3,BC0,acc[3][0]); acc[3][1]=MF(aC3,BC1,acc[3][1]);                 \
    acc[3][2]=MF(aC3,BC2,acc[3][2]); acc[3][3]=MF(aC3,BC3,acc[3][3]);                 \
    __builtin_amdgcn_s_setprio(0);                                                    \
    if (RA) { aC0 = LD8(An_ + oa0); aC1 = LD8(An_ + oa1);                             \
              aC2 = LD8(An_ + oa2); aC3 = LD8(An_ + oa3); }                           \
    __builtin_amdgcn_s_setprio(1);                                                    \
    acc[4][0]=MF(x4_,BC0,acc[4][0]); acc[4][1]=MF(x4_,BC1,acc[4][1]);                 \
    acc[4][2]=MF(x4_,BC2,acc[4][2]); acc[4][3]=MF(x4_,BC3,acc[4][3]);                 \
    acc[5][0]=MF(x5_,BC0,acc[5][0]); acc[5][1]=MF(x5_,BC1,acc[5][1]);                 \
    acc[5][2]=MF(x5_,BC2,acc[5][2]); acc[5][3]=MF(x5_,BC3,acc[5][3]);                 \
    acc[6][0]=MF(x6_,BC0,acc[6][0]); acc[6][1]=MF(x6_,BC1,acc[6][1]);                 \
    acc[6][2]=MF(x6_,BC2,acc[6][2]); acc[6][3]=MF(x6_,BC3,acc[6][3]);                 \
    acc[7][0]=MF(x7_,BC0,acc[7][0]); acc[7][1]=MF(x7_,BC1,acc[7][1]);                 \
    acc[7][2]=MF(x7_,BC2,acc[7][2]); acc[7][3]=MF(x7_,BC3,acc[7][3]);                 \
    __builtin_amdgcn_s_setprio(0);                                                    \
} while (0)

__global__ __launch_bounds__(512, 2) void gemm_bf16_pipe(
        const bf16_t* __restrict__ A, const bf16_t* __restrict__ B,
        const float* __restrict__ bias, float* __restrict__ C) {

    __shared__ __align__(16) bf16_t Asm[NBUF][BM * BK];   // 4 x 16 KB
    __shared__ __align__(16) bf16_t Bsm[NBUF][BN * BK];   // 4 x 16 KB -> 128 KiB

    const int tid  = threadIdx.x;
    const int lane = tid & 63;
    const int wave = tid >> 6;        // 0..7
    const int wm   = wave >> 2;       // 0..1 : M half (128 rows)
    const int wn   = wave & 3;        // 0..3 : N quarter (64 cols)

    // XCD-aware swizzle (nwg = 512, divisible by 8 -> bijective)
    const int nwg = gridDim.x;
    const int cpx = nwg >> 3;
    const int swz = (blockIdx.x & 7) * cpx + (blockIdx.x >> 3);
    const int ntn = N_DIM / BN;       // 16
    const int brow = (swz / ntn) * BM;
    const int bcol = (swz % ntn) * BN;

    // ---- staging geometry (r2-proven): tile = 256 rows x 32 bf16 = 16KB =
    // 1024 x 16B slots; slot s holds (row = s>>2, chunk = (s&3)^((s>>3)&3)).
    const int slot0 = wave * 128 + lane;
    const int slot1 = slot0 + 64;
    const int r0 = slot0 >> 2, c0 = ((slot0 & 3) ^ ((slot0 >> 3) & 3)) << 3;
    const int r1 = slot1 >> 2, c1 = ((slot1 & 3) ^ ((slot1 >> 3) & 3)) << 3;
    const bf16_t* gA0 = A + (size_t)(brow + r0) * K_DIM + c0;
    const bf16_t* gA1 = A + (size_t)(brow + r1) * K_DIM + c1;
    const bf16_t* gB0 = B + (size_t)(bcol + r0) * K_DIM + c0;
    const bf16_t* gB1 = B + (size_t)(bcol + r1) * K_DIM + c1;
    const int dst0 = wave * 1024;     // elem offset (slot * 8)
    const int dst1 = dst0 + 512;

    // ---- ds_read fragment offsets (r2-proven, measured 0 bank conflicts)
    const int fr = lane & 15;
    const int cc = lane >> 4;         // k-chunk 0..3 (k = cc*8)
#define AOFF(p, mi) ({ int row_ = wm*128 + (p)*64 + (mi)*16 + fr; \
                       row_*32 + ((cc ^ ((row_ >> 1) & 3)) << 3); })
#define BOFF(ni)    ({ int row_ = wn*64 + (ni)*16 + fr; \
                       row_*32 + ((cc ^ ((row_ >> 1) & 3)) << 3); })
    const int oa0 = AOFF(0,0), oa1 = AOFF(0,1), oa2 = AOFF(0,2), oa3 = AOFF(0,3);
    const int oa4 = AOFF(1,0), oa5 = AOFF(1,1), oa6 = AOFF(1,2), oa7 = AOFF(1,3);
    const int ob0 = BOFF(0), ob1 = BOFF(1), ob2 = BOFF(2), ob3 = BOFF(3);

    f32x4 acc[8][4];
#pragma unroll
    for (int i = 0; i < 8; i++)
#pragma unroll
        for (int j = 0; j < 4; j++)
            acc[i][j] = (f32x4){0.f, 0.f, 0.f, 0.f};

    // ---- prologue: stage tiles 0,1,2; land tile 0; pre-read tile-0 cluster-1 frags
    STAGE_A(0) STAGE_B(0)
    STAGE_A(1) STAGE_B(1)
    STAGE_A(2) STAGE_B(2)
    asm volatile("s_waitcnt vmcnt(8)" ::: "memory");
    __builtin_amdgcn_s_barrier();

    bf16x8 aC0 = LD8(&Asm[0][0] + oa0);
    bf16x8 aC1 = LD8(&Asm[0][0] + oa1);
    bf16x8 aC2 = LD8(&Asm[0][0] + oa2);
    bf16x8 aC3 = LD8(&Asm[0][0] + oa3);
    bf16x8 bE0 = LD8(&Bsm[0][0] + ob0);
    bf16x8 bE1 = LD8(&Bsm[0][0] + ob1);
    bf16x8 bE2 = LD8(&Bsm[0][0] + ob2);
    bf16x8 bE3 = LD8(&Bsm[0][0] + ob3);
    bf16x8 bO0 = bE0, bO1 = bE1, bO2 = bE2, bO3 = bE3;   // defined init

    // ---- main loop: 4-tile unroll (ring immediates + B parity)
    for (int t = 0; t < 124; t += 4) {
        TILE(t+0, 1, "s_waitcnt vmcnt(4)", 1, bE0,bE1,bE2,bE3, bO0,bO1,bO2,bO3);
        TILE(t+1, 1, "s_waitcnt vmcnt(4)", 1, bO0,bO1,bO2,bO3, bE0,bE1,bE2,bE3);
        TILE(t+2, 1, "s_waitcnt vmcnt(4)", 1, bE0,bE1,bE2,bE3, bO0,bO1,bO2,bO3);
        TILE(t+3, 1, "s_waitcnt vmcnt(4)", 1, bO0,bO1,bO2,bO3, bE0,bE1,bE2,bE3);
    }
    TILE(124, 1, "s_waitcnt vmcnt(4)", 1, bE0,bE1,bE2,bE3, bO0,bO1,bO2,bO3);
    TILE(125, 0, "s_waitcnt vmcnt(4)", 1, bO0,bO1,bO2,bO3, bE0,bE1,bE2,bE3);
    TILE(126, 0, "s_waitcnt vmcnt(0)", 1, bE0,bE1,bE2,bE3, bO0,bO1,bO2,bO3);
    TILE(127, 0, "s_nop 0",            0, bO0,bO1,bO2,bO3, bE0,bE1,bE2,bE3);

    // ---- epilogue: C/D layout col = lane&15, row = (lane>>4)*4 + r
    const int cc0 = bcol + wn * 64 + (lane & 15);
    const int rr0 = brow + wm * 128 + (lane >> 4) * 4;

    float bv[4];
#pragma unroll
    for (int ni = 0; ni < 4; ni++) bv[ni] = bias[cc0 + ni * 16];

#pragma unroll
    for (int p = 0; p < 2; p++) {
#pragma unroll
        for (int i = 0; i < 4; i++) {
#pragma unroll
            for (int r = 0; r < 4; r++) {
                const size_t row = (size_t)(rr0 + p * 64 + i * 16 + r);
#pragma unroll
                for (int ni = 0; ni < 4; ni++) {
                    C[row * N_DIM + cc0 + ni * 16] = acc[p * 4 + i][ni][r] + bv[ni];
                }
            }
        }
    }
}

// ---------------- safety-net fallback (no workspace): plain fp32 dot ----------------
__global__ void gemm_fallback_f32(const float* __restrict__ A, const float* __restrict__ B,
                                  const float* __restrict__ bias, float* __restrict__ C) {
    int n = blockIdx.x * 16 + threadIdx.x;
    int m = blockIdx.y * 16 + threadIdx.y;
    if (m >= M_DIM || n >= N_DIM) return;
    const float4* a = reinterpret_cast<const float4*>(A + (size_t)m * K_DIM);
    const float4* b = reinterpret_cast<const float4*>(B + (size_t)n * K_DIM);
    float s = 0.f;
    for (int k = 0; k < K_DIM / 4; k++) {
        float4 x = a[k], y = b[k];
        s += x.x * y.x + x.y * y.y + x.z * y.z + x.w * y.w;
    }
    C[(size_t)m * N_DIM + n] = s + bias[n];
}

extern "C" void kernel_launch(void* const* d_in, const int* in_sizes, int n_in,
                              void* d_out, int out_size, void* d_ws, size_t ws_size,
                              hipStream_t stream) {
    const float* x    = (const float*)d_in[0];   // [M][K] fp32
    const float* w    = (const float*)d_in[1];   // [N][K] fp32 (B^T layout)
    const float* bias = (const float*)d_in[2];   // [N] fp32
    float* out = (float*)d_out;

    const size_t xb = (size_t)M_DIM * K_DIM * sizeof(bf16_t);   // 64 MB
    const size_t wb = (size_t)N_DIM * K_DIM * sizeof(bf16_t);   // 32 MB

    if (ws_size >= xb + wb) {
        bf16_t* xbf = (bf16_t*)d_ws;
        bf16_t* wbf = (bf16_t*)((char*)d_ws + xb);

        cvt_f32_to_bf16<<<2048, 256, 0, stream>>>(x, xbf, (M_DIM * K_DIM) / 8);
        cvt_f32_to_bf16<<<1024, 256, 0, stream>>>(w, wbf, (N_DIM * K_DIM) / 8);

        const int grid = (M_DIM / BM) * (N_DIM / BN);   // 32 * 16 = 512
        gemm_bf16_pipe<<<grid, 512, 0, stream>>>(xbf, wbf, bias, out);
    } else {
        dim3 block(16, 16);
        dim3 grid(N_DIM / 16, M_DIM / 16);
        gemm_fallback_f32<<<grid, block, 0, stream>>>(x, w, bias, out);
    }
}

// Round 9
// 304.647 us; speedup vs baseline: 8.4260x; 1.1071x over previous
//
#include <hip/hip_runtime.h>
#include <hip/hip_bf16.h>
#include <stdint.h>

#define M_DIM 8192
#define N_DIM 4096   // OUT_F
#define K_DIM 4096   // IN_F

#define BM 256
#define BN 256
#define BK 64
#define NT (K_DIM / BK)   // 64 K-tiles

typedef __bf16 bf16_t;
typedef __attribute__((ext_vector_type(8))) __bf16 bf16x8;
typedef __attribute__((ext_vector_type(4))) float f32x4;

// ---------------- fp32 -> bf16 convert (vectorized, grid-stride) ----------------
__global__ void cvt_f32_to_bf16(const float* __restrict__ in, bf16_t* __restrict__ out, int n8) {
    int stride = gridDim.x * blockDim.x;
    for (int i = blockIdx.x * blockDim.x + threadIdx.x; i < n8; i += stride) {
        const float4* p = reinterpret_cast<const float4*>(in) + 2 * (size_t)i;
        float4 v0 = p[0];
        float4 v1 = p[1];
        bf16x8 o;
        o[0] = (bf16_t)v0.x; o[1] = (bf16_t)v0.y; o[2] = (bf16_t)v0.z; o[3] = (bf16_t)v0.w;
        o[4] = (bf16_t)v1.x; o[5] = (bf16_t)v1.y; o[6] = (bf16_t)v1.z; o[7] = (bf16_t)v1.w;
        *(reinterpret_cast<bf16x8*>(out) + (size_t)i) = o;
    }
}

// ---------------- 256x256 bf16 GEMM, faithful m201-style 8-phase (BK=64) ----------------
// A: [M][K] bf16 row-major; B: [N][K] bf16 row-major (weight = B^T layout);
// C = A*B^T + bias, fp32 out.
//
// 2-dbuf x 2-half LDS (128 KiB). Per K-tile (BK=64), 4 phases; each:
//   { ds_read subtile | stage one half-tile (2 gload_lds) ; [lgkmcnt(8) if 12 reads]
//     s_barrier ; lgkmcnt(0) ; setprio(1) ; 16 MFMA ; setprio(0) ; s_barrier }
// NO sched_barrier (m141). Counted vmcnt(2) ONCE per tile at ph3:
//   stage order: ph0 -> (T+1) A-h1, ph1 -> (T+1) B-h0, ph2 -> (T+1) B-h1,
//                ph3 -> (T+2) A-h0.
//   At ph3 pre-vmcnt: outstanding = [T+1 Ah0 (T-1 ph3), T+1 Ah1, T+1 Bh0,
//   T+1 Bh1, T+2 Ah0] = 10 loads; vmcnt(2) drains the 8 oldest = all of T+1,
//   leaves T+2 Ah0 flying (never drain to 0 in steady state).
// WAR: T+2 Ah0 overwrites buf[T&1] A-h0, last read at T ph2 (reads complete
//   before each wave's lgkmcnt(0), hence before ph2's closing barrier; the
//   stage is issued after that barrier). All other stages hit the opposite buf.
// Swizzle: row stride 128 B = one bank wrap; chunk' = chunk ^ (row&7); read
//   pattern spreads 64 lanes 8-per-16B-position, perfectly balanced (r2-class,
//   measured-0-conflict property).

#define MF(a, b, c) __builtin_amdgcn_mfma_f32_16x16x32_bf16((a), (b), (c), 0, 0, 0)
#define LD8(p) (*reinterpret_cast<const bf16x8*>(p))
#define GLL(src, dst) __builtin_amdgcn_global_load_lds(                               \
    (const __attribute__((address_space(1))) void*)(src),                             \
    (__attribute__((address_space(3))) void*)(dst), 16, 0, 0)

// Stage one half (H=0/1) of K-tile TT into buffer BUF (elements: half = 128 rows x 64)
#define STAGE_AH(TT, H, BUF) { const size_t ko_ = (size_t)(TT) * BK;                  \
    GLL(gA_ + ko_ + (size_t)(H) * 524288,          &Asm[BUF][H][dst0]);               \
    GLL(gA_ + ko_ + (size_t)(H) * 524288 + 262144, &Asm[BUF][H][dst1]); }
#define STAGE_BH(TT, H, BUF) { const size_t ko_ = (size_t)(TT) * BK;                  \
    GLL(gB_ + ko_ + (size_t)(H) * 524288,          &Bsm[BUF][H][dst0]);               \
    GLL(gB_ + ko_ + (size_t)(H) * 524288 + 262144, &Bsm[BUF][H][dst1]); }

// 16 MFMA for one quadrant: acc rows RB..RB+3, cols NB0,NB1 with B frags bxny
#define QMM(RB, NB0, NB1, bq00, bq01, bq10, bq11)                                     \
    acc[RB+0][NB0]=MF(a00,bq00,acc[RB+0][NB0]); acc[RB+0][NB1]=MF(a00,bq10,acc[RB+0][NB1]); \
    acc[RB+1][NB0]=MF(a10,bq00,acc[RB+1][NB0]); acc[RB+1][NB1]=MF(a10,bq10,acc[RB+1][NB1]); \
    acc[RB+0][NB0]=MF(a01,bq01,acc[RB+0][NB0]); acc[RB+0][NB1]=MF(a01,bq11,acc[RB+0][NB1]); \
    acc[RB+1][NB0]=MF(a11,bq01,acc[RB+1][NB0]); acc[RB+1][NB1]=MF(a11,bq11,acc[RB+1][NB1]); \
    acc[RB+2][NB0]=MF(a20,bq00,acc[RB+2][NB0]); acc[RB+2][NB1]=MF(a20,bq10,acc[RB+2][NB1]); \
    acc[RB+3][NB0]=MF(a30,bq00,acc[RB+3][NB0]); acc[RB+3][NB1]=MF(a30,bq10,acc[RB+3][NB1]); \
    acc[RB+2][NB0]=MF(a21,bq01,acc[RB+2][NB0]); acc[RB+2][NB1]=MF(a21,bq11,acc[RB+2][NB1]); \
    acc[RB+3][NB0]=MF(a31,bq01,acc[RB+3][NB0]); acc[RB+3][NB1]=MF(a31,bq11,acc[RB+3][NB1]);

#define BAR() __builtin_amdgcn_s_barrier()
#define LGKM0() asm volatile("s_waitcnt lgkmcnt(0)" ::: "memory")
#define PRIO(x) __builtin_amdgcn_s_setprio(x)

#define TILE(T, STG, STG3, VMSTR) do {                                                \
    const int c_ = (T) & 1, n_ = ((T) + 1) & 1;                                       \
    bf16_t* Ab_ = &Asm[c_][wm][0];                                                    \
    bf16_t* Bb_ = &Bsm[c_][wnh][wnl * 4096];                                          \
    /* ---- ph0: read A m0-3 (8) + B n0-1 (4); stage (T+1) A-h1 */                    \
    bf16x8 a00 = LD8(Ab_ + roA0),        a01 = LD8(Ab_ + roA1);                       \
    bf16x8 a10 = LD8(Ab_ + roA0 + 1024), a11 = LD8(Ab_ + roA1 + 1024);                \
    bf16x8 a20 = LD8(Ab_ + roA0 + 2048), a21 = LD8(Ab_ + roA1 + 2048);                \
    bf16x8 a30 = LD8(Ab_ + roA0 + 3072), a31 = LD8(Ab_ + roA1 + 3072);                \
    bf16x8 b00 = LD8(Bb_ + roA0),        b01 = LD8(Bb_ + roA1);                       \
    bf16x8 b10 = LD8(Bb_ + roA0 + 1024), b11 = LD8(Bb_ + roA1 + 1024);                \
    if (STG) STAGE_AH((T) + 1, 1, n_);                                                \
    asm volatile("s_waitcnt lgkmcnt(8)" ::: "memory");                                \
    BAR(); LGKM0(); PRIO(1); QMM(0, 0, 1, b00, b01, b10, b11); PRIO(0); BAR();        \
    /* ---- ph1: read B n2-3 (4); stage (T+1) B-h0 */                                 \
    bf16x8 b20 = LD8(Bb_ + roA0 + 2048), b21 = LD8(Bb_ + roA1 + 2048);                \
    bf16x8 b30 = LD8(Bb_ + roA0 + 3072), b31 = LD8(Bb_ + roA1 + 3072);                \
    if (STG) STAGE_BH((T) + 1, 0, n_);                                                \
    BAR(); LGKM0(); PRIO(1); QMM(0, 2, 3, b20, b21, b30, b31); PRIO(0); BAR();        \
    /* ---- ph2: read A m4-7 (8, reuse regs); stage (T+1) B-h1 */                     \
    a00 = LD8(Ab_ + roA0 + 4096); a01 = LD8(Ab_ + roA1 + 4096);                       \
    a10 = LD8(Ab_ + roA0 + 5120); a11 = LD8(Ab_ + roA1 + 5120);                       \
    a20 = LD8(Ab_ + roA0 + 6144); a21 = LD8(Ab_ + roA1 + 6144);                       \
    a30 = LD8(Ab_ + roA0 + 7168); a31 = LD8(Ab_ + roA1 + 7168);                       \
    if (STG) STAGE_BH((T) + 1, 1, n_);                                                \
    BAR(); LGKM0(); PRIO(1); QMM(4, 0, 1, b00, b01, b10, b11); PRIO(0); BAR();        \
    /* ---- ph3: no reads; stage (T+2) A-h0; counted vmcnt once per tile */           \
    if (STG3) STAGE_AH((T) + 2, 0, c_);                                               \
    asm volatile(VMSTR ::: "memory");                                                 \
    BAR(); PRIO(1); QMM(4, 2, 3, b20, b21, b30, b31); PRIO(0); BAR();                 \
} while (0)

__global__ __launch_bounds__(512, 2) void gemm_bf16_8ph(
        const bf16_t* __restrict__ A, const bf16_t* __restrict__ B,
        const float* __restrict__ bias, float* __restrict__ C) {

    // 2 dbuf x 2 halves x (128 rows x 64 bf16) each for A and B = 128 KiB
    __shared__ __align__(16) bf16_t Asm[2][2][128 * 64];
    __shared__ __align__(16) bf16_t Bsm[2][2][128 * 64];

    const int tid  = threadIdx.x;
    const int lane = tid & 63;
    const int wave = tid >> 6;        // 0..7
    const int wm   = wave >> 2;       // 0..1 : M half (A-half index)
    const int wn   = wave & 3;        // 0..3 : N quarter (64 cols)
    const int wnl  = wn & 1;          // row offset (x64) inside B-half
    const int wnh  = wn >> 1;         // B-half index

    // XCD-aware swizzle (nwg = 512, divisible by 8 -> bijective)
    const int nwg = gridDim.x;
    const int cpx = nwg >> 3;
    const int swz = (blockIdx.x & 7) * cpx + (blockIdx.x >> 3);
    const int ntn = N_DIM / BN;       // 16
    const int brow = (swz / ntn) * BM;
    const int bcol = (swz % ntn) * BN;

    // ---- staging geometry: half = 128 rows x 64 bf16 = 16 KB = 1024 slots of 16B.
    // slot s: row = s>>3, stored chunk position = s&7, holds global chunk
    // (s&7) ^ (row&7). Thread covers slots {tid, 512+tid} (2 gload_lds/half).
    const int row0 = tid >> 3;                    // 0..63 (j=0); j=1 adds 64 rows
    const int chg  = (tid & 7) ^ (row0 & 7);      // same for j=0,1 (row&7 invariant)
    const bf16_t* gA_ = A + (size_t)(brow + row0) * K_DIM + chg * 8;
    const bf16_t* gB_ = B + (size_t)(bcol + row0) * K_DIM + chg * 8;
    // elem offsets inside STAGE macros: H*524288 = H*128*K, +262144 = 64*K (j=1)
    const int dst0 = wave * 512;                  // elems: slot (wave*64) * 8
    const int dst1 = 4096 + wave * 512;           // elems: slot (512 + wave*64) * 8

    // ---- ds_read offsets (elems) within a half: frag (local row lr, chunk)
    // lr = [wnl*64 +] i*16 + fr ; chunk = ks*4 + cc ; swz chunk' = chunk ^ (lr&7)
    // lr&7 == fr&7 for all frags -> two per-thread bases, +i*1024 immediates.
    const int fr = lane & 15;
    const int cc = lane >> 4;         // 0..3
    const int roA0 = fr * 64 + ((cc ^ (fr & 7)) << 3);            // ks=0
    const int roA1 = fr * 64 + (((4 + cc) ^ (fr & 7)) << 3);      // ks=1

    f32x4 acc[8][4];
#pragma unroll
    for (int i = 0; i < 8; i++)
#pragma unroll
        for (int j = 0; j < 4; j++)
            acc[i][j] = (f32x4){0.f, 0.f, 0.f, 0.f};

    // ---- prologue: stage tile 0 (4 halves) + tile 1 A-h0; drain tile 0
    STAGE_AH(0, 0, 0) STAGE_AH(0, 1, 0)
    STAGE_BH(0, 0, 0) STAGE_BH(0, 1, 0)
    STAGE_AH(1, 0, 1)
    asm volatile("s_waitcnt vmcnt(2)" ::: "memory");
    __builtin_amdgcn_s_barrier();

    // ---- main loop
    for (int t = 0; t < NT - 2; ++t)
        TILE(t, 1, 1, "s_waitcnt vmcnt(2)");
    TILE(NT - 2, 1, 0, "s_waitcnt vmcnt(0)");
    TILE(NT - 1, 0, 0, "s_nop 0");

    // ---- epilogue: C/D layout col = lane&15, row = (lane>>4)*4 + r
    const int cc0 = bcol + wn * 64 + (lane & 15);
    const int rr0 = brow + wm * 128 + (lane >> 4) * 4;

    float bv[4];
#pragma unroll
    for (int ni = 0; ni < 4; ni++) bv[ni] = bias[cc0 + ni * 16];

#pragma unroll
    for (int p = 0; p < 2; p++) {
#pragma unroll
        for (int i = 0; i < 4; i++) {
#pragma unroll
            for (int r = 0; r < 4; r++) {
                const size_t row = (size_t)(rr0 + p * 64 + i * 16 + r);
#pragma unroll
                for (int ni = 0; ni < 4; ni++) {
                    C[row * N_DIM + cc0 + ni * 16] = acc[p * 4 + i][ni][r] + bv[ni];
                }
            }
        }
    }
}

// ---------------- safety-net fallback (no workspace): plain fp32 dot ----------------
__global__ void gemm_fallback_f32(const float* __restrict__ A, const float* __restrict__ B,
                                  const float* __restrict__ bias, float* __restrict__ C) {
    int n = blockIdx.x * 16 + threadIdx.x;
    int m = blockIdx.y * 16 + threadIdx.y;
    if (m >= M_DIM || n >= N_DIM) return;
    const float4* a = reinterpret_cast<const float4*>(A + (size_t)m * K_DIM);
    const float4* b = reinterpret_cast<const float4*>(B + (size_t)n * K_DIM);
    float s = 0.f;
    for (int k = 0; k < K_DIM / 4; k++) {
        float4 x = a[k], y = b[k];
        s += x.x * y.x + x.y * y.y + x.z * y.z + x.w * y.w;
    }
    C[(size_t)m * N_DIM + n] = s + bias[n];
}

extern "C" void kernel_launch(void* const* d_in, const int* in_sizes, int n_in,
                              void* d_out, int out_size, void* d_ws, size_t ws_size,
                              hipStream_t stream) {
    const float* x    = (const float*)d_in[0];   // [M][K] fp32
    const float* w    = (const float*)d_in[1];   // [N][K] fp32 (B^T layout)
    const float* bias = (const float*)d_in[2];   // [N] fp32
    float* out = (float*)d_out;

    const size_t xb = (size_t)M_DIM * K_DIM * sizeof(bf16_t);   // 64 MB
    const size_t wb = (size_t)N_DIM * K_DIM * sizeof(bf16_t);   // 32 MB

    if (ws_size >= xb + wb) {
        bf16_t* xbf = (bf16_t*)d_ws;
        bf16_t* wbf = (bf16_t*)((char*)d_ws + xb);

        cvt_f32_to_bf16<<<2048, 256, 0, stream>>>(x, xbf, (M_DIM * K_DIM) / 8);
        cvt_f32_to_bf16<<<1024, 256, 0, stream>>>(w, wbf, (N_DIM * K_DIM) / 8);

        const int grid = (M_DIM / BM) * (N_DIM / BN);   // 32 * 16 = 512
        gemm_bf16_8ph<<<grid, 512, 0, stream>>>(xbf, wbf, bias, out);
    } else {
        dim3 block(16, 16);
        dim3 grid(N_DIM / 16, M_DIM / 16);
        gemm_fallback_f32<<<grid, block, 0, stream>>>(x, w, bias, out);
    }
}